// Round 2
// baseline (794.218 us; speedup 1.0000x reference)
//
#include <hip/hip_runtime.h>
#include <hip/hip_bf16.h>
#include <stdint.h>

typedef short bf16x8 __attribute__((ext_vector_type(8)));
typedef float f32x4  __attribute__((ext_vector_type(4)));

#define DIM 512
#define NROWS 4096
#define MREFS 65536

__device__ __forceinline__ unsigned short f2bf(float v) {
  __hip_bfloat16 h = __float2bfloat16(v);
  return *reinterpret_cast<unsigned short*>(&h);
}

__device__ __forceinline__ void gl_lds16(const unsigned short* g, unsigned short* l) {
  __builtin_amdgcn_global_load_lds(
      (const __attribute__((address_space(1))) unsigned int*)g,
      (__attribute__((address_space(3))) unsigned int*)l, 16, 0, 0);
}

// ---------------- prep: normalize x rows -> bf16 ----------------
__global__ __launch_bounds__(256) void prep_x(const float* __restrict__ x,
                                              unsigned short* __restrict__ xbf) {
  int row  = blockIdx.x * 4 + (threadIdx.x >> 6);
  int lane = threadIdx.x & 63;
  const float* xr = x + (size_t)row * DIM + lane * 8;
  f32x4 a = *(const f32x4*)xr;
  f32x4 b = *(const f32x4*)(xr + 4);
  float s = a.x*a.x + a.y*a.y + a.z*a.z + a.w*a.w
          + b.x*b.x + b.y*b.y + b.z*b.z + b.w*b.w;
  #pragma unroll
  for (int off = 1; off < 64; off <<= 1) s += __shfl_xor(s, off);
  float scale = 1.0f / fmaxf(sqrtf(s), 1e-12f);
  bf16x8 o;
  o[0] = (short)f2bf(a.x * scale);
  o[1] = (short)f2bf(a.y * scale);
  o[2] = (short)f2bf(a.z * scale);
  o[3] = (short)f2bf(a.w * scale);
  o[4] = (short)f2bf(b.x * scale);
  o[5] = (short)f2bf(b.y * scale);
  o[6] = (short)f2bf(b.z * scale);
  o[7] = (short)f2bf(b.w * scale);
  *(bf16x8*)(xbf + (size_t)row * DIM + lane * 8) = o;
}

// ---------------- prep: cast one ref chunk f32 -> bf16 ----------------
__global__ __launch_bounds__(256) void prep_r_chunk(const float* __restrict__ r,
                                                    unsigned short* __restrict__ rb) {
  size_t i = ((size_t)blockIdx.x * 256 + threadIdx.x) * 8;
  f32x4 a = *(const f32x4*)(r + i);
  f32x4 b = *(const f32x4*)(r + i + 4);
  bf16x8 o;
  o[0] = (short)f2bf(a.x); o[1] = (short)f2bf(a.y);
  o[2] = (short)f2bf(a.z); o[3] = (short)f2bf(a.w);
  o[4] = (short)f2bf(b.x); o[5] = (short)f2bf(b.y);
  o[6] = (short)f2bf(b.z); o[7] = (short)f2bf(b.w);
  *(bf16x8*)(rb + i) = o;
}

__global__ __launch_bounds__(256) void init_state(float* __restrict__ st) {
  st[(size_t)blockIdx.x * 256 + threadIdx.x] = -3.0e38f;
}

// ---------------- GEMM: S[row][col] = sum_k X[row][k]*R[col][k], bf16 out ----------------
// 128x128 C tile, BK=64, 4 waves (2x2 of 64x64), m97-style 2-barrier loop.
__global__ __launch_bounds__(256) void gemm_s(const unsigned short* __restrict__ A,
                                              const unsigned short* __restrict__ B,
                                              unsigned short* __restrict__ S,
                                              int scols) {
  __shared__ unsigned short As[128 * 64];
  __shared__ unsigned short Bs[128 * 64];
  int bid = blockIdx.x;
  int rowblk = bid & 31;       // 4096/128 = 32 row blocks
  int colblk = bid >> 5;
  int tid  = threadIdx.x;
  int lane = tid & 63;
  int wid  = tid >> 6;
  int wr = wid >> 1, wc = wid & 1;

  f32x4 acc[4][4];
  #pragma unroll
  for (int m = 0; m < 4; ++m)
    #pragma unroll
    for (int n = 0; n < 4; ++n) acc[m][n] = f32x4{0.f, 0.f, 0.f, 0.f};

  const unsigned short* Abase = A + (size_t)rowblk * 128 * DIM;
  const unsigned short* Bbase = B + (size_t)colblk * 128 * DIM;

  for (int ks = 0; ks < DIM / 64; ++ks) {
    #pragma unroll
    for (int j = 0; j < 4; ++j) {
      int c = tid + 256 * j;         // 1024 16B chunks per tile
      int trow = c >> 3;             // 128 rows
      int k8 = c & 7;                // 8 x 16B along K
      gl_lds16(Abase + (size_t)trow * DIM + ks * 64 + k8 * 8, As + c * 8);
      gl_lds16(Bbase + (size_t)trow * DIM + ks * 64 + k8 * 8, Bs + c * 8);
    }
    __syncthreads();
    #pragma unroll
    for (int kk = 0; kk < 2; ++kk) {
      bf16x8 af[4], bfr[4];
      #pragma unroll
      for (int m = 0; m < 4; ++m) {
        int r_ = wr * 64 + m * 16 + (lane & 15);
        af[m] = *(const bf16x8*)(As + r_ * 64 + kk * 32 + (lane >> 4) * 8);
      }
      #pragma unroll
      for (int n = 0; n < 4; ++n) {
        int c_ = wc * 64 + n * 16 + (lane & 15);
        bfr[n] = *(const bf16x8*)(Bs + c_ * 64 + kk * 32 + (lane >> 4) * 8);
      }
      #pragma unroll
      for (int m = 0; m < 4; ++m)
        #pragma unroll
        for (int n = 0; n < 4; ++n)
          acc[m][n] = __builtin_amdgcn_mfma_f32_16x16x32_bf16(af[m], bfr[n], acc[m][n], 0, 0, 0);
    }
    __syncthreads();
  }

  // epilogue: C layout col=lane&15, row=(lane>>4)*4+q  [m89-verified]
  int r0 = rowblk * 128 + wr * 64 + (lane >> 4) * 4;
  int c0 = colblk * 128 + wc * 64 + (lane & 15);
  #pragma unroll
  for (int m = 0; m < 4; ++m)
    #pragma unroll
    for (int n = 0; n < 4; ++n)
      #pragma unroll
      for (int q = 0; q < 4; ++q)
        S[(size_t)(r0 + m * 16 + q) * scols + (c0 + n * 16)] = f2bf(acc[m][n][q]);
}

// ---------------- per-row running top-16 (largest S) ----------------
__global__ __launch_bounds__(256) void select_topk(const unsigned short* __restrict__ S,
                                                   float* __restrict__ state,
                                                   int scols) {
  int wid = threadIdx.x >> 6, lane = threadIdx.x & 63;
  int row = blockIdx.x * 4 + wid;
  float* st = state + (size_t)row * 16;
  float t[16];  // wave-uniform, sorted descending
  #pragma unroll
  for (int i = 0; i < 16; ++i) t[i] = st[i];
  const unsigned short* Sr = S + (size_t)row * scols;
  int iters = scols >> 9;  // 512 values (64 lanes x 8) per iter
  for (int it = 0; it < iters; ++it) {
    bf16x8 v8 = *(const bf16x8*)(Sr + (size_t)it * 512 + lane * 8);
    float f[8];
    #pragma unroll
    for (int j = 0; j < 8; ++j)
      f[j] = __uint_as_float(((unsigned)(unsigned short)v8[j]) << 16);
    float mx = f[0];
    #pragma unroll
    for (int j = 1; j < 8; ++j) mx = fmaxf(mx, f[j]);
    if (__any(mx > t[15])) {
      #pragma unroll
      for (int j = 0; j < 8; ++j) {
        unsigned long long mask = __ballot(f[j] > t[15]);
        while (mask) {
          int leader = __ffsll(mask) - 1;
          float v2 = __shfl(f[j], leader);
          if (v2 > t[15]) {  // re-check vs tightened threshold
            bool gt[16];
            #pragma unroll
            for (int i = 0; i < 16; ++i) gt[i] = v2 > t[i];
            #pragma unroll
            for (int i = 15; i >= 1; --i) t[i] = gt[i] ? (gt[i - 1] ? t[i - 1] : v2) : t[i];
            t[0] = gt[0] ? v2 : t[0];
          }
          mask &= mask - 1;
        }
      }
    }
  }
  if (lane == 0) {
    #pragma unroll
    for (int i = 0; i < 16; ++i) st[i] = t[i];
  }
}

// ---------------- weights: d=sqrt(2-2S), w=exp(-d), L1-normalize ----------------
__global__ __launch_bounds__(256) void weights_k(const float* __restrict__ state,
                                                 float* __restrict__ out) {
  int row = blockIdx.x * 256 + threadIdx.x;
  float w[16];
  float sum = 0.f;
  #pragma unroll
  for (int i = 0; i < 16; ++i) {
    float s = state[(size_t)row * 16 + i];            // descending S = ascending distance
    float d = sqrtf(fmaxf(2.0f - 2.0f * s, 1e-12f));
    float e = expf(-d);
    w[i] = e;
    sum += e;
  }
  float inv = 1.0f / fmaxf(sum, 1e-12f);
  #pragma unroll
  for (int i = 0; i < 16; ++i) out[(size_t)row * 16 + i] = w[i] * inv;
}

extern "C" void kernel_launch(void* const* d_in, const int* in_sizes, int n_in,
                              void* d_out, int out_size, void* d_ws, size_t ws_size,
                              hipStream_t stream) {
  const float* x    = (const float*)d_in[0];
  const float* refs = (const float*)d_in[1];
  float* out = (float*)d_out;
  char* ws = (char*)d_ws;

  // layout: xbf (4 MB) | state (256 KB) | rbfc (chunk*512*2) | schunk (4096*chunk*2)
  const size_t xbf_bytes   = (size_t)NROWS * DIM * 2;        // 4 MB
  const size_t state_bytes = (size_t)NROWS * 16 * 4;         // 256 KB
  const size_t base = xbf_bytes + state_bytes;

  unsigned short* xbf = (unsigned short*)ws;
  float* state        = (float*)(ws + xbf_bytes);

  // per-chunk need: chunk*DIM*2 (rbfc) + NROWS*chunk*2 (schunk) = chunk*9216 bytes
  int chunk = 8192;
  while (chunk > 512 && base + (size_t)chunk * (DIM * 2 + NROWS * 2) > ws_size) chunk >>= 1;
  if (base + (size_t)chunk * (DIM * 2 + NROWS * 2) > ws_size) return;  // can't run safely
  int nch = MREFS / chunk;

  unsigned short* rbfc   = (unsigned short*)(ws + base);
  unsigned short* schunk = (unsigned short*)(ws + base + (size_t)chunk * DIM * 2);

  hipLaunchKernelGGL(prep_x, dim3(NROWS / 4), dim3(256), 0, stream, x, xbf);
  hipLaunchKernelGGL(init_state, dim3((NROWS * 16) / 256), dim3(256), 0, stream, state);

  for (int c = 0; c < nch; ++c) {
    hipLaunchKernelGGL(prep_r_chunk, dim3((chunk * (DIM / 8)) / 256), dim3(256), 0, stream,
                       refs + (size_t)c * chunk * DIM, rbfc);
    hipLaunchKernelGGL(gemm_s, dim3((chunk / 128) * 32), dim3(256), 0, stream,
                       xbf, rbfc, schunk, chunk);
    hipLaunchKernelGGL(select_topk, dim3(NROWS / 4), dim3(256), 0, stream,
                       schunk, state, chunk);
  }
  hipLaunchKernelGGL(weights_k, dim3(NROWS / 256), dim3(256), 0, stream, state, out);
}

// Round 3
// 772.548 us; speedup vs baseline: 1.0281x; 1.0281x over previous
//
#include <hip/hip_runtime.h>
#include <hip/hip_bf16.h>
#include <stdint.h>

typedef short bf16x8 __attribute__((ext_vector_type(8)));
typedef float f32x4  __attribute__((ext_vector_type(4)));

#define DIM 512
#define NROWS 4096
#define MREFS 65536
#define BM 256
#define BK 64
#define NT (DIM / BK)   // 8 K-tiles

__device__ __forceinline__ unsigned short f2bf(float v) {
  __hip_bfloat16 h = __float2bfloat16(v);
  return *reinterpret_cast<unsigned short*>(&h);
}

__device__ __forceinline__ void gl_lds16(const unsigned short* g, unsigned short* l) {
  __builtin_amdgcn_global_load_lds(
      (const __attribute__((address_space(1))) unsigned int*)g,
      (__attribute__((address_space(3))) unsigned int*)l, 16, 0, 0);
}

// ---------------- prep: normalize x rows -> bf16 ----------------
__global__ __launch_bounds__(256) void prep_x(const float* __restrict__ x,
                                              unsigned short* __restrict__ xbf) {
  int row  = blockIdx.x * 4 + (threadIdx.x >> 6);
  int lane = threadIdx.x & 63;
  const float* xr = x + (size_t)row * DIM + lane * 8;
  f32x4 a = *(const f32x4*)xr;
  f32x4 b = *(const f32x4*)(xr + 4);
  float s = a.x*a.x + a.y*a.y + a.z*a.z + a.w*a.w
          + b.x*b.x + b.y*b.y + b.z*b.z + b.w*b.w;
  #pragma unroll
  for (int off = 1; off < 64; off <<= 1) s += __shfl_xor(s, off);
  float scale = 1.0f / fmaxf(sqrtf(s), 1e-12f);
  bf16x8 o;
  o[0] = (short)f2bf(a.x * scale); o[1] = (short)f2bf(a.y * scale);
  o[2] = (short)f2bf(a.z * scale); o[3] = (short)f2bf(a.w * scale);
  o[4] = (short)f2bf(b.x * scale); o[5] = (short)f2bf(b.y * scale);
  o[6] = (short)f2bf(b.z * scale); o[7] = (short)f2bf(b.w * scale);
  *(bf16x8*)(xbf + (size_t)row * DIM + lane * 8) = o;
}

// ---------------- prep: cast all refs f32 -> bf16 ----------------
__global__ __launch_bounds__(256) void prep_r(const float* __restrict__ r,
                                              unsigned short* __restrict__ rb) {
  size_t i = ((size_t)blockIdx.x * 256 + threadIdx.x) * 8;
  f32x4 a = *(const f32x4*)(r + i);
  f32x4 b = *(const f32x4*)(r + i + 4);
  bf16x8 o;
  o[0] = (short)f2bf(a.x); o[1] = (short)f2bf(a.y);
  o[2] = (short)f2bf(a.z); o[3] = (short)f2bf(a.w);
  o[4] = (short)f2bf(b.x); o[5] = (short)f2bf(b.y);
  o[6] = (short)f2bf(b.z); o[7] = (short)f2bf(b.w);
  *(bf16x8*)(rb + i) = o;
}

__global__ __launch_bounds__(256) void init_state(float* __restrict__ st) {
  st[(size_t)blockIdx.x * 256 + threadIdx.x] = -3.0e38f;
}

// ================= 256x256 8-phase bf16 GEMM (T1+T2+T3+T4+T5) =================
// S[row][col] = sum_k A[row][k] * B[col][k]; A,B row-major bf16, K=512.
// 8 waves (2Mx4N), per-wave 128x64 output, BK=64, LDS 128 KiB double-buffered.
// Swizzle: phys_slot = slot ^ (row&7) on 16B slots, applied at stage-source AND read.

#define PH_SYNC() { __builtin_amdgcn_s_barrier(); \
  asm volatile("s_waitcnt lgkmcnt(0)" ::: "memory"); \
  __builtin_amdgcn_sched_barrier(0); \
  __builtin_amdgcn_s_setprio(1); }
#define PH_END() { __builtin_amdgcn_s_setprio(0); __builtin_amdgcn_s_barrier(); }
#define PH_ENDV() { __builtin_amdgcn_s_setprio(0); \
  asm volatile("s_waitcnt vmcnt(4)" ::: "memory"); \
  __builtin_amdgcn_s_barrier(); }
#define MF(mm, nn, aa, bb) \
  acc[mm][nn] = __builtin_amdgcn_mfma_f32_16x16x32_bf16(aa, bb, acc[mm][nn], 0, 0, 0)

__global__ __launch_bounds__(512) void gemm8(const unsigned short* __restrict__ A,
                                             const unsigned short* __restrict__ B,
                                             unsigned short* __restrict__ S,
                                             int scols) {
  __shared__ unsigned short As_[2][BM * BK];
  __shared__ unsigned short Bs_[2][BM * BK];

  // T1: bijective XCD swizzle (nwg % 8 == 0 guaranteed by launcher)
  int nwg = gridDim.x;
  int bid = blockIdx.x;
  int cpx = nwg >> 3;
  int swz = (bid & 7) * cpx + (bid >> 3);
  int rowblk = swz & 15;             // 4096/256 = 16 row blocks (fastest)
  int colblk = swz >> 4;

  int tid  = threadIdx.x;
  int lane = tid & 63;
  int wid  = tid >> 6;
  int wr = wid >> 2;                 // 0..1
  int wc = wid & 3;                  // 0..3
  int l15 = lane & 15;
  int lg  = lane >> 4;               // 0..3

  const unsigned short* Ab = A + (size_t)rowblk * BM * DIM;
  const unsigned short* Bb = B + (size_t)colblk * BM * DIM;

  f32x4 acc[8][4];
  #pragma unroll
  for (int m = 0; m < 8; ++m)
    #pragma unroll
    for (int n = 0; n < 4; ++n) acc[m][n] = f32x4{0.f, 0.f, 0.f, 0.f};

  // stage one 128-row half-tile (16 KB) of matrix gb at K-tile kt into lbuf
  auto stage_half = [&](const unsigned short* gb, unsigned short* lbuf, int half, int kt) {
    int kc = kt < NT ? kt : NT - 1;   // clamp overrun staging (data never consumed)
    #pragma unroll
    for (int j = 0; j < 2; ++j) {
      int c = tid + j * 512;
      int row = half * 128 + (c >> 3);
      int ls = (c & 7) ^ (row & 7);   // pre-swizzled source slot (involution)
      const unsigned short* src = gb + (size_t)row * DIM + kc * BK + ls * 8;
      unsigned short* dst = (unsigned short*)((char*)lbuf + half * 16384 + wid * 1024 + j * 8192);
      gl_lds16(src, dst);             // linear LDS dest: wave base + lane*16
    }
  };
  // swizzled fragment read: slot = kk*4 + lg
  auto ldfrag = [&](const unsigned short* buf, int r, int slot) -> bf16x8 {
    return *(const bf16x8*)(buf + r * BK + (slot ^ (r & 7)) * 8);
  };

  bf16x8 a[4][2], b0[2][2], b1[2][2];

  // ---- prologue: t0 all 4 halves -> dbuf0; t1 B-halves -> dbuf1 ----
  stage_half(Ab, As_[0], 0, 0); stage_half(Ab, As_[0], 1, 0);
  stage_half(Bb, Bs_[0], 0, 0); stage_half(Bb, Bs_[0], 1, 0);
  stage_half(Bb, Bs_[1], 0, 1); stage_half(Bb, Bs_[1], 1, 1);
  asm volatile("s_waitcnt vmcnt(4)" ::: "memory");   // t0 resident; t1-B (4) in flight
  __builtin_amdgcn_s_barrier();

  for (int i = 0; i < NT / 2; ++i) {
    int tb = 2 * i + 1, tc = 2 * i + 2, td = 2 * i + 3;
    // ---- ph1: (ta) Q m0-3 x n0-1 ---- stage A-h0(tb)->dbuf1
    #pragma unroll
    for (int m = 0; m < 4; ++m) { int r = wr * 128 + m * 16 + l15;
      a[m][0] = ldfrag(As_[0], r, lg); a[m][1] = ldfrag(As_[0], r, 4 + lg); }
    #pragma unroll
    for (int n = 0; n < 2; ++n) { int r = wc * 64 + n * 16 + l15;
      b0[n][0] = ldfrag(Bs_[0], r, lg); b0[n][1] = ldfrag(Bs_[0], r, 4 + lg); }
    stage_half(Ab, As_[1], 0, tb);
    PH_SYNC();
    #pragma unroll
    for (int m = 0; m < 4; ++m)
      #pragma unroll
      for (int n = 0; n < 2; ++n) { MF(m, n, a[m][0], b0[n][0]); MF(m, n, a[m][1], b0[n][1]); }
    PH_END();
    // ---- ph2: (ta) Q m0-3 x n2-3 ---- stage A-h1(tb)->dbuf1
    #pragma unroll
    for (int n = 0; n < 2; ++n) { int r = wc * 64 + (n + 2) * 16 + l15;
      b1[n][0] = ldfrag(Bs_[0], r, lg); b1[n][1] = ldfrag(Bs_[0], r, 4 + lg); }
    stage_half(Ab, As_[1], 1, tb);
    PH_SYNC();
    #pragma unroll
    for (int m = 0; m < 4; ++m)
      #pragma unroll
      for (int n = 0; n < 2; ++n) { MF(m, n + 2, a[m][0], b1[n][0]); MF(m, n + 2, a[m][1], b1[n][1]); }
    PH_END();
    // ---- ph3: (ta) Q m4-7 x n0-1 ---- stage B-h0(tc)->dbuf0 (B freed after ph2)
    #pragma unroll
    for (int m = 0; m < 4; ++m) { int r = wr * 128 + 64 + m * 16 + l15;
      a[m][0] = ldfrag(As_[0], r, lg); a[m][1] = ldfrag(As_[0], r, 4 + lg); }
    stage_half(Bb, Bs_[0], 0, tc);
    PH_SYNC();
    #pragma unroll
    for (int m = 0; m < 4; ++m)
      #pragma unroll
      for (int n = 0; n < 2; ++n) { MF(m + 4, n, a[m][0], b0[n][0]); MF(m + 4, n, a[m][1], b0[n][1]); }
    PH_END();
    // ---- ph4: (ta) Q m4-7 x n2-3 ---- stage B-h1(tc)->dbuf0; vmcnt(4): tb resident
    stage_half(Bb, Bs_[0], 1, tc);
    PH_SYNC();
    #pragma unroll
    for (int m = 0; m < 4; ++m)
      #pragma unroll
      for (int n = 0; n < 2; ++n) { MF(m + 4, n + 2, a[m][0], b1[n][0]); MF(m + 4, n + 2, a[m][1], b1[n][1]); }
    PH_ENDV();
    // ---- ph5: (tb) Q m0-3 x n0-1 ---- stage A-h0(tc)->dbuf0 (A freed after ph3)
    #pragma unroll
    for (int m = 0; m < 4; ++m) { int r = wr * 128 + m * 16 + l15;
      a[m][0] = ldfrag(As_[1], r, lg); a[m][1] = ldfrag(As_[1], r, 4 + lg); }
    #pragma unroll
    for (int n = 0; n < 2; ++n) { int r = wc * 64 + n * 16 + l15;
      b0[n][0] = ldfrag(Bs_[1], r, lg); b0[n][1] = ldfrag(Bs_[1], r, 4 + lg); }
    stage_half(Ab, As_[0], 0, tc);
    PH_SYNC();
    #pragma unroll
    for (int m = 0; m < 4; ++m)
      #pragma unroll
      for (int n = 0; n < 2; ++n) { MF(m, n, a[m][0], b0[n][0]); MF(m, n, a[m][1], b0[n][1]); }
    PH_END();
    // ---- ph6: (tb) Q m0-3 x n2-3 ---- stage A-h1(tc)->dbuf0
    #pragma unroll
    for (int n = 0; n < 2; ++n) { int r = wc * 64 + (n + 2) * 16 + l15;
      b1[n][0] = ldfrag(Bs_[1], r, lg); b1[n][1] = ldfrag(Bs_[1], r, 4 + lg); }
    stage_half(Ab, As_[0], 1, tc);
    PH_SYNC();
    #pragma unroll
    for (int m = 0; m < 4; ++m)
      #pragma unroll
      for (int n = 0; n < 2; ++n) { MF(m, n + 2, a[m][0], b1[n][0]); MF(m, n + 2, a[m][1], b1[n][1]); }
    PH_END();
    // ---- ph7: (tb) Q m4-7 x n0-1 ---- stage B-h0(td)->dbuf1 (B freed after ph6)
    #pragma unroll
    for (int m = 0; m < 4; ++m) { int r = wr * 128 + 64 + m * 16 + l15;
      a[m][0] = ldfrag(As_[1], r, lg); a[m][1] = ldfrag(As_[1], r, 4 + lg); }
    stage_half(Bb, Bs_[1], 0, td);
    PH_SYNC();
    #pragma unroll
    for (int m = 0; m < 4; ++m)
      #pragma unroll
      for (int n = 0; n < 2; ++n) { MF(m + 4, n, a[m][0], b0[n][0]); MF(m + 4, n, a[m][1], b0[n][1]); }
    PH_END();
    // ---- ph8: (tb) Q m4-7 x n2-3 ---- stage B-h1(td)->dbuf1; vmcnt(4): tc resident
    stage_half(Bb, Bs_[1], 1, td);
    PH_SYNC();
    #pragma unroll
    for (int m = 0; m < 4; ++m)
      #pragma unroll
      for (int n = 0; n < 2; ++n) { MF(m + 4, n + 2, a[m][0], b1[n][0]); MF(m + 4, n + 2, a[m][1], b1[n][1]); }
    PH_ENDV();
  }

  // drain outstanding stage loads before LDS deallocation / epilogue
  asm volatile("s_waitcnt vmcnt(0)" ::: "memory");

  // epilogue: C frag layout col=lane&15, row=(lane>>4)*4+q  [m89-verified]
  int r0 = rowblk * BM + wr * 128 + lg * 4;
  int c0 = colblk * BM + wc * 64 + l15;
  #pragma unroll
  for (int m = 0; m < 8; ++m)
    #pragma unroll
    for (int n = 0; n < 4; ++n)
      #pragma unroll
      for (int q = 0; q < 4; ++q)
        S[(size_t)(r0 + m * 16 + q) * scols + (c0 + n * 16)] = f2bf(acc[m][n][q]);
}

// ---------------- per-row running top-16 (largest S) ----------------
__global__ __launch_bounds__(256) void select_topk(const unsigned short* __restrict__ S,
                                                   float* __restrict__ state,
                                                   int scols) {
  int wid = threadIdx.x >> 6, lane = threadIdx.x & 63;
  int row = blockIdx.x * 4 + wid;
  float* st = state + (size_t)row * 16;
  float t[16];  // wave-uniform, sorted descending
  #pragma unroll
  for (int i = 0; i < 16; ++i) t[i] = st[i];
  const unsigned short* Sr = S + (size_t)row * scols;
  int iters = scols >> 9;  // 512 values (64 lanes x 8) per iter
  for (int it = 0; it < iters; ++it) {
    bf16x8 v8 = *(const bf16x8*)(Sr + (size_t)it * 512 + lane * 8);
    float f[8];
    #pragma unroll
    for (int j = 0; j < 8; ++j)
      f[j] = __uint_as_float(((unsigned)(unsigned short)v8[j]) << 16);
    float mx = f[0];
    #pragma unroll
    for (int j = 1; j < 8; ++j) mx = fmaxf(mx, f[j]);
    if (__any(mx > t[15])) {
      #pragma unroll
      for (int j = 0; j < 8; ++j) {
        unsigned long long mask = __ballot(f[j] > t[15]);
        while (mask) {
          int leader = __ffsll(mask) - 1;
          float v2 = __shfl(f[j], leader);
          if (v2 > t[15]) {
            bool gt[16];
            #pragma unroll
            for (int i = 0; i < 16; ++i) gt[i] = v2 > t[i];
            #pragma unroll
            for (int i = 15; i >= 1; --i) t[i] = gt[i] ? (gt[i - 1] ? t[i - 1] : v2) : t[i];
            t[0] = gt[0] ? v2 : t[0];
          }
          mask &= mask - 1;
        }
      }
    }
  }
  if (lane == 0) {
    #pragma unroll
    for (int i = 0; i < 16; ++i) st[i] = t[i];
  }
}

// ---------------- weights: d=sqrt(2-2S), w=exp(-d), L1-normalize ----------------
__global__ __launch_bounds__(256) void weights_k(const float* __restrict__ state,
                                                 float* __restrict__ out) {
  int row = blockIdx.x * 256 + threadIdx.x;
  float w[16];
  float sum = 0.f;
  #pragma unroll
  for (int i = 0; i < 16; ++i) {
    float s = state[(size_t)row * 16 + i];
    float d = sqrtf(fmaxf(2.0f - 2.0f * s, 1e-12f));
    float e = expf(-d);
    w[i] = e;
    sum += e;
  }
  float inv = 1.0f / fmaxf(sum, 1e-12f);
  #pragma unroll
  for (int i = 0; i < 16; ++i) out[(size_t)row * 16 + i] = w[i] * inv;
}

extern "C" void kernel_launch(void* const* d_in, const int* in_sizes, int n_in,
                              void* d_out, int out_size, void* d_ws, size_t ws_size,
                              hipStream_t stream) {
  const float* x    = (const float*)d_in[0];
  const float* refs = (const float*)d_in[1];
  float* out = (float*)d_out;
  char* ws = (char*)d_ws;

  // layout: xbf (4 MiB) | state (256 KiB) | rbf (64 MiB) | schunk (4096*chunk*2)
  const size_t xbf_bytes   = (size_t)NROWS * DIM * 2;
  const size_t state_bytes = (size_t)NROWS * 16 * 4;
  const size_t rbf_bytes   = (size_t)MREFS * DIM * 2;
  const size_t base = xbf_bytes + state_bytes + rbf_bytes;

  unsigned short* xbf = (unsigned short*)ws;
  float* state        = (float*)(ws + xbf_bytes);
  unsigned short* rbf = (unsigned short*)(ws + xbf_bytes + state_bytes);
  unsigned short* schunk = (unsigned short*)(ws + base);

  int chunk = 16384;
  while (chunk > 2048 && base + (size_t)NROWS * chunk * 2 > ws_size) chunk >>= 1;
  if (base + (size_t)NROWS * chunk * 2 > ws_size) return;
  int nch = MREFS / chunk;

  hipLaunchKernelGGL(prep_x, dim3(NROWS / 4), dim3(256), 0, stream, x, xbf);
  hipLaunchKernelGGL(prep_r, dim3((MREFS * (DIM / 8)) / 256), dim3(256), 0, stream, refs, rbf);
  hipLaunchKernelGGL(init_state, dim3((NROWS * 16) / 256), dim3(256), 0, stream, state);

  for (int c = 0; c < nch; ++c) {
    hipLaunchKernelGGL(gemm8, dim3((NROWS / BM) * (chunk / BM)), dim3(512), 0, stream,
                       xbf, rbf + (size_t)c * chunk * DIM, schunk, chunk);
    hipLaunchKernelGGL(select_topk, dim3(NROWS / 4), dim3(256), 0, stream,
                       schunk, state, chunk);
  }
  hipLaunchKernelGGL(weights_k, dim3(NROWS / 256), dim3(256), 0, stream, state, out);
}